// Round 3
// baseline (298.615 us; speedup 1.0000x reference)
//
#include <hip/hip_runtime.h>
#include <stdint.h>

// CrossNetwork: x:[16384,512] f32, W:[4,512,512] f32 (torch Linear), b:[4,512] f32
// out:[16384, 4*512] f32 = concat of layer outputs.
//
// Algebra: the scalar-residual loop collapses to x_eff = x_l + c_l*1 with
//   c = 0; for j<l: c += dot(x_l,x_j) + c*sum(x_j)
// and (x_l + c*1) @ W^T = x_l @ W^T + c * rowsum(W).
//
// R3 structure (5 dispatches):
//   prep: W->bf16 + wsum, x0->bf16 + sums[0], zero atomic accumulators
//   gemm l=0..3: m97-style MFMA GEMM; prologue computes c-chain for its rows
//     from dots/sums (written by previous gemm); epilogue writes f32 out +
//     bf16 xb_{l+1} AND block-partial sums/dots via shuffle+LDS+atomicAdd.

#define BROWS 16384
#define DIM 512
#define NL 4
#define OUTSTRIDE (NL * DIM)

#define BM 128
#define BN 128
#define BK 32

typedef unsigned short ushort_t;
typedef __attribute__((ext_vector_type(8))) short bf16x8;
typedef __attribute__((ext_vector_type(4))) float f32x4;

__device__ inline ushort_t f32_to_bf16(float f) {
    union { float f; uint32_t u; } v; v.f = f;
    uint32_t u = v.u;
    uint32_t r = (u + 0x7fffu + ((u >> 16) & 1u)) >> 16;   // RNE
    return (ushort_t)r;
}

__device__ inline float bf16_bits_to_f32(ushort_t u) {
    union { uint32_t u; float f; } v; v.u = ((uint32_t)u) << 16; return v.f;
}

__device__ inline float wave_reduce_sum(float v) {
    #pragma unroll
    for (int off = 32; off > 0; off >>= 1) v += __shfl_down(v, off, 64);
    return v;
}

// reduce across the 16-lane nlane group (offsets 1,2,4,8 stay within group)
__device__ inline float quad16_reduce(float v) {
    #pragma unroll
    for (int off = 8; off > 0; off >>= 1) v += __shfl_xor(v, off, 64);
    return v;
}

// ---------------------------------------------------------------------------
// prep: blocks [0,4096): x0 rows (4/block, wave-per-row) -> xb0 + sums[0]
//       blocks [4096,4608): W rows (4/block) -> Wb + wsum
//       blocks [4608,4800): zero sums[1..3] + dots (12*16384 f32, exact)
// ---------------------------------------------------------------------------
__global__ __launch_bounds__(256) void prep_kernel(
    const float* __restrict__ x0, const float* __restrict__ W,
    ushort_t* __restrict__ xb0, ushort_t* __restrict__ Wb,
    float* __restrict__ wsum, float* __restrict__ sums,
    float* __restrict__ zbase)
{
    int blk = blockIdx.x;
    int wave = threadIdx.x >> 6, lane = threadIdx.x & 63;
    if (blk >= 4608) {
        int idx = (blk - 4608) * 1024 + threadIdx.x * 4;
        float4 z = {0.f, 0.f, 0.f, 0.f};
        *(float4*)(zbase + idx) = z;
        return;
    }
    const float* src; ushort_t* dst; float* red_out; int row;
    if (blk < 4096) {
        row = blk * 4 + wave;
        src = x0 + (size_t)row * DIM;
        dst = xb0 + (size_t)row * DIM;
        red_out = sums;             // sums[0][row]
    } else {
        row = (blk - 4096) * 4 + wave;   // 0..2047 = l*512+e
        src = W + (size_t)row * DIM;
        dst = Wb + (size_t)row * DIM;
        red_out = wsum;
    }
    const float* xp = src + lane * 8;
    float4 a = ((const float4*)xp)[0];
    float4 c4 = ((const float4*)xp)[1];
    float f[8] = {a.x, a.y, a.z, a.w, c4.x, c4.y, c4.z, c4.w};
    bf16x8 o;
    float s = 0.f;
    #pragma unroll
    for (int i = 0; i < 8; ++i) {
        o[i] = (short)f32_to_bf16(f[i]);
        s += f[i];
    }
    *(bf16x8*)(dst + lane * 8) = o;
    s = wave_reduce_sum(s);
    if (lane == 0) red_out[row] = s;
}

// ---------------------------------------------------------------------------
// GEMM layer l: y[b][e] = sum_d x_l[b][d]*W[e][d] + c[b]*wsum[e] + bias[e]
//   prologue: c[b] chain from dots[(l-1)*3+j] / sums[j]  (j<l)
//   K-loop: m97-verified 128x128, BK=32, global_load_lds w16, 4 waves 2x2
//   epilogue: out (f32) + xb_next (bf16) + partial sums[l+1], dots[l*3+j]
// grid (4,128), 256 threads.
// ---------------------------------------------------------------------------
__global__ __launch_bounds__(256) void gemm_kernel(
    const ushort_t* __restrict__ xb,    // base of all xb layers [4][16384][512]
    const ushort_t* __restrict__ Wb,    // this layer's W [512][512] bf16
    const float* __restrict__ bias,     // [512]
    const float* __restrict__ wsum,     // [512]
    float* __restrict__ sums,           // [4][16384]
    float* __restrict__ dots,           // [3][3][16384]  (lp1-1, j, b)
    float* __restrict__ out,            // stride OUTSTRIDE, col-offset applied
    ushort_t* __restrict__ xb_next,     // bf16 or nullptr (l==3)
    int l)
{
    __shared__ __align__(16) ushort_t sA[BM * BK];
    __shared__ __align__(16) ushort_t sB[BN * BK];
    __shared__ float cv[BM];
    __shared__ float redS[2][BM];
    __shared__ float redD[2][BM][3];

    int tid  = threadIdx.x;
    int wave = tid >> 6;
    int lane = tid & 63;
    int wm = wave >> 1, wn = wave & 1;
    int bm = blockIdx.y * BM;
    int bn = blockIdx.x * BN;
    const ushort_t* A = xb + (size_t)l * BROWS * DIM;

    // prologue: c-chain for this block's 128 rows
    if (tid < BM) {
        float c = 0.f;
        if (l > 0) {
            const float* db = dots + (size_t)(l - 1) * 3 * BROWS;
            for (int j = 0; j < l; ++j)
                c = c + db[j * BROWS + bm + tid] + c * sums[j * BROWS + bm + tid];
        }
        cv[tid] = c;
    }
    // (first __syncthreads in K-loop makes cv visible)

    f32x4 acc[4][4] = {};
    int srow = lane >> 2;            // 0..15
    int scol = (lane & 3) * 8;       // 0,8,16,24

    for (int k0 = 0; k0 < DIM; k0 += BK) {
        __syncthreads();
        #pragma unroll
        for (int t2 = 0; t2 < 2; ++t2) {
            int r = wave * 32 + t2 * 16;
            const ushort_t* gA = A  + (size_t)(bm + r + srow) * DIM + k0 + scol;
            const ushort_t* gB = Wb + (size_t)(bn + r + srow) * DIM + k0 + scol;
            __builtin_amdgcn_global_load_lds(
                (const __attribute__((address_space(1))) void*)gA,
                (__attribute__((address_space(3))) void*)(sA + r * BK), 16, 0, 0);
            __builtin_amdgcn_global_load_lds(
                (const __attribute__((address_space(1))) void*)gB,
                (__attribute__((address_space(3))) void*)(sB + r * BK), 16, 0, 0);
        }
        __syncthreads();

        int q = lane >> 4;
        int rr = lane & 15;
        bf16x8 af[4], bfr[4];
        #pragma unroll
        for (int mi = 0; mi < 4; ++mi)
            af[mi] = *(const bf16x8*)(sA + (wm * 64 + mi * 16 + rr) * BK + q * 8);
        #pragma unroll
        for (int ni = 0; ni < 4; ++ni)
            bfr[ni] = *(const bf16x8*)(sB + (wn * 64 + ni * 16 + rr) * BK + q * 8);
        #pragma unroll
        for (int mi = 0; mi < 4; ++mi)
            #pragma unroll
            for (int ni = 0; ni < 4; ++ni)
                acc[mi][ni] = __builtin_amdgcn_mfma_f32_16x16x32_bf16(
                    af[mi], bfr[ni], acc[mi][ni], 0, 0, 0);
    }

    // Epilogue. C/D layout (m89/m91): col = lane&15, row = (lane>>4)*4 + reg
    int q = lane >> 4, nlane = lane & 15;
    #pragma unroll
    for (int ni = 0; ni < 4; ++ni) {
        int n_g = bn + wn * 64 + ni * 16 + nlane;
        float ws = wsum[n_g];
        float bs = bias[n_g];
        #pragma unroll
        for (int mi = 0; mi < 4; ++mi) {
            #pragma unroll
            for (int r = 0; r < 4; ++r) {
                int m_l = wm * 64 + mi * 16 + q * 4 + r;
                float v = acc[mi][ni][r] + cv[m_l] * ws + bs;
                acc[mi][ni][r] = v;   // keep y in regs for the stats pass
                out[(size_t)(bm + m_l) * OUTSTRIDE + n_g] = v;
                if (xb_next)
                    xb_next[(size_t)(bm + m_l) * DIM + n_g] = f32_to_bf16(v);
            }
        }
    }

    // Fused stats: partial row-sums and dots over this block's 128 cols.
    if (l < 3) {
        bool need_sums = (l <= 1);   // sums[3] is never consumed
        if (need_sums) {
            #pragma unroll
            for (int mi = 0; mi < 4; ++mi) {
                #pragma unroll
                for (int r = 0; r < 4; ++r) {
                    float p = acc[mi][0][r] + acc[mi][1][r] + acc[mi][2][r] + acc[mi][3][r];
                    p = quad16_reduce(p);
                    if (nlane == 0)
                        redS[wn][wm * 64 + mi * 16 + q * 4 + r] = p;
                }
            }
        }
        for (int j = 0; j <= l; ++j) {
            const ushort_t* xj = xb + (size_t)j * BROWS * DIM;
            #pragma unroll
            for (int mi = 0; mi < 4; ++mi) {
                #pragma unroll
                for (int r = 0; r < 4; ++r) {
                    int m_l = wm * 64 + mi * 16 + q * 4 + r;
                    const ushort_t* xr = xj + (size_t)(bm + m_l) * DIM;
                    float pd = 0.f;
                    #pragma unroll
                    for (int ni = 0; ni < 4; ++ni) {
                        int n_g = bn + wn * 64 + ni * 16 + nlane;
                        pd += acc[mi][ni][r] * bf16_bits_to_f32(xr[n_g]);
                    }
                    pd = quad16_reduce(pd);
                    if (nlane == 0)
                        redD[wn][m_l][j] = pd;
                }
            }
        }
        __syncthreads();
        if (tid < BM) {
            int m_g = bm + tid;
            if (need_sums)
                atomicAdd(&sums[(size_t)(l + 1) * BROWS + m_g],
                          redS[0][tid] + redS[1][tid]);
            for (int j = 0; j <= l; ++j)
                atomicAdd(&dots[((size_t)l * 3 + j) * BROWS + m_g],
                          redD[0][tid][j] + redD[1][tid][j]);
        }
    }
}

// ---------------------------------------------------------------------------
extern "C" void kernel_launch(void* const* d_in, const int* in_sizes, int n_in,
                              void* d_out, int out_size, void* d_ws, size_t ws_size,
                              hipStream_t stream) {
    (void)in_sizes; (void)n_in; (void)out_size; (void)ws_size;
    const float* x0   = (const float*)d_in[0];
    const float* W    = (const float*)d_in[1];
    const float* bias = (const float*)d_in[2];
    float* out = (float*)d_out;

    char* ws = (char*)d_ws;
    // workspace layout (bytes):
    //   xb   : 4 * 16384*512 * 2 = 67,108,864
    //   Wb   : 4 * 512*512  * 2 =  2,097,152
    //   wsum : 4 * 512 * 4      =      8,192
    //   sums : 4 * 16384 * 4    =    262,144
    //   dots : 9 * 16384 * 4    =    589,824   (~67 MB total)
    ushort_t* xb   = (ushort_t*)ws;
    ushort_t* Wb   = (ushort_t*)(ws + 67108864);
    float*    wsum = (float*)   (ws + 69206016);
    float*    sums = (float*)   (ws + 69214208);
    float*    dots = (float*)   (ws + 69476352);

    // zero region: sums[1..3] + dots = 12*16384 f32 == 192 blocks * 1024
    prep_kernel<<<4800, 256, 0, stream>>>(x0, W, xb, Wb, wsum, sums,
                                          sums + BROWS);

    dim3 ggrid(DIM / BN, BROWS / BM);   // (4, 128)
    for (int l = 0; l < NL; ++l) {
        gemm_kernel<<<ggrid, 256, 0, stream>>>(
            xb,
            Wb + (size_t)l * DIM * DIM,
            bias + l * DIM,
            wsum + l * DIM,
            sums, dots,
            out + l * DIM,
            (l < NL - 1) ? (xb + (size_t)(l + 1) * BROWS * DIM) : nullptr,
            l);
    }
}